// Round 5
// baseline (271.845 us; speedup 1.0000x reference)
//
#include <hip/hip_runtime.h>
#include <hip/hip_bf16.h>

// ---------- types ----------
typedef __attribute__((ext_vector_type(8))) short short8;   // 8 x bf16 (4 VGPRs)
typedef __attribute__((ext_vector_type(4))) float f32x4;    // 16x16 MFMA accumulator

typedef unsigned short u16;

__device__ __forceinline__ u16 f32_to_bf16(float f) {
    unsigned int u = __float_as_uint(f);
    u += 0x7fffu + ((u >> 16) & 1u);   // round-to-nearest-even
    return (u16)(u >> 16);
}
__device__ __forceinline__ float bf16_to_f32(u16 h) {
    return __uint_as_float(((unsigned int)h) << 16);
}

// async global->LDS, 16B per lane; LDS dest = wave-uniform base + lane*16
__device__ __forceinline__ void gload16(const u16* g, u16* lds_base) {
    __builtin_amdgcn_global_load_lds(
        (const __attribute__((address_space(1))) void*)g,
        (__attribute__((address_space(3))) void*)lds_base, 16, 0, 0);
}

// ---------- cast fp32 -> bf16, 4 elems/thread ----------
__global__ void cast_f32_bf16_x4(const float* __restrict__ in,
                                 u16* __restrict__ out, int n4) {
    int i = blockIdx.x * blockDim.x + threadIdx.x;
    if (i >= n4) return;
    float4 v = ((const float4*)in)[i];
    ushort4 o;
    o.x = f32_to_bf16(v.x); o.y = f32_to_bf16(v.y);
    o.z = f32_to_bf16(v.z); o.w = f32_to_bf16(v.w);
    ((ushort4*)out)[i] = o;
}

// ---------- output store helpers ----------
__device__ __forceinline__ void store_c(float* p, float v) { *p = v; }
__device__ __forceinline__ void store_c(u16* p, float v)   { *p = f32_to_bf16(v); }

// ---------- GEMM: C[M,N] = A[M,K] * Bt[N,K]^T  (both row-major, contiguous K) ----
// 128x128 block tile, BK=64, 256 threads (4 waves 2x2), each wave 64x64 via 4x4
// of v_mfma_f32_16x16x32_bf16. Staging via global_load_lds width=16. LDS
// unpadded (global_load_lds lane mapping); conflicts broken by XOR chunk
// swizzle: row r, slot p holds global chunk p ^ (r&7). This exact read pattern
// measured 0 SQ_LDS_BANK_CONFLICT (R3); the 32x32 variant measured 6.29M — do
// not switch shapes without re-measuring conflicts.

template <typename OutT>
__global__ __launch_bounds__(256) void gemm_bt(
    const u16* __restrict__ Abase, const u16* __restrict__ Bbase,
    OutT* __restrict__ Cbase, int M, int N, int K,
    int lda, int ldb, int ldc,
    long long sAb, long long sBb, long long sCb)
{
    const u16* A  = Abase + (long long)blockIdx.z * sAb;
    const u16* Bt = Bbase + (long long)blockIdx.z * sBb;
    OutT*      C  = Cbase + (long long)blockIdx.z * sCb;

    __shared__ u16 sA[128 * 64];
    __shared__ u16 sB[128 * 64];

    const int t    = threadIdx.x;
    const int lane = t & 63;
    const int wave = t >> 6;
    const int wm = (wave >> 1) * 64;
    const int wn = (wave & 1) * 64;
    const int lr = lane & 15;            // fragment row (A) / col (B)
    const int row0 = blockIdx.y * 128;
    const int col0 = blockIdx.x * 128;

    f32x4 acc[4][4];
#pragma unroll
    for (int i = 0; i < 4; ++i)
#pragma unroll
        for (int j = 0; j < 4; ++j)
            acc[i][j] = (f32x4){0.f, 0.f, 0.f, 0.f};

    const int srow = lane >> 3;                    // 0..7 within 8-row group
    const int gc   = (lane & 7) ^ srow;            // swizzled global chunk
    for (int k0 = 0; k0 < K; k0 += 64) {
        __syncthreads();
#pragma unroll
        for (int c = 0; c < 4; ++c) {
            const int rb = c * 32 + wave * 8;      // wave-uniform row base
            const int r  = rb + srow;
            gload16(A  + (long long)(row0 + r) * lda + k0 + gc * 8, &sA[rb * 64]);
            gload16(Bt + (long long)(col0 + r) * ldb + k0 + gc * 8, &sB[rb * 64]);
        }
        __syncthreads();

#pragma unroll
        for (int kk = 0; kk < 64; kk += 32) {
            const int cb = (lane >> 4) + (kk >> 3);   // chunk index 0..7
            const int sl = (cb ^ (lr & 7)) * 8;       // swizzled slot (elems)
            short8 af[4], bf[4];
#pragma unroll
            for (int i = 0; i < 4; ++i) {
                af[i] = *(const short8*)(&sA[(wm + i * 16 + lr) * 64 + sl]);
                bf[i] = *(const short8*)(&sB[(wn + i * 16 + lr) * 64 + sl]);
            }
#pragma unroll
            for (int i = 0; i < 4; ++i)
#pragma unroll
                for (int j = 0; j < 4; ++j)
                    acc[i][j] = __builtin_amdgcn_mfma_f32_16x16x32_bf16(
                        af[i], bf[j], acc[i][j], 0, 0, 0);
        }
    }

    // C/D layout: col = lane&15, row = (lane>>4)*4 + reg   [m89/m91-verified]
    const int cr = (lane >> 4) * 4;
    const int cc = lane & 15;
#pragma unroll
    for (int i = 0; i < 4; ++i)
#pragma unroll
        for (int j = 0; j < 4; ++j)
#pragma unroll
            for (int r = 0; r < 4; ++r) {
                int grow = row0 + wm + i * 16 + cr + r;
                int gcol = col0 + wn + j * 16 + cc;
                store_c(&C[(long long)grow * ldc + gcol], acc[i][j][r]);
            }
}

// ---------- GEMM 128x64 tile (for PV: boosts block count / occupancy) ----------
// 4 waves = 4 row-strips of 32 rows x 64 cols; per wave 2x4 of 16x16x32.
__global__ __launch_bounds__(256) void gemm_bt_n64(
    const u16* __restrict__ Abase, const u16* __restrict__ Bbase,
    float* __restrict__ Cbase, int M, int N, int K,
    int lda, int ldb, int ldc,
    long long sAb, long long sBb, long long sCb)
{
    const u16* A  = Abase + (long long)blockIdx.z * sAb;
    const u16* Bt = Bbase + (long long)blockIdx.z * sBb;
    float*     C  = Cbase + (long long)blockIdx.z * sCb;

    __shared__ u16 sA[128 * 64];
    __shared__ u16 sB[64 * 64];

    const int t    = threadIdx.x;
    const int lane = t & 63;
    const int wave = t >> 6;
    const int wm = wave * 32;            // wave row-strip
    const int lr = lane & 15;
    const int row0 = blockIdx.y * 128;
    const int col0 = blockIdx.x * 64;

    f32x4 acc[2][4];
#pragma unroll
    for (int i = 0; i < 2; ++i)
#pragma unroll
        for (int j = 0; j < 4; ++j)
            acc[i][j] = (f32x4){0.f, 0.f, 0.f, 0.f};

    const int srow = lane >> 3;
    const int gc   = (lane & 7) ^ srow;
    for (int k0 = 0; k0 < K; k0 += 64) {
        __syncthreads();
#pragma unroll
        for (int c = 0; c < 4; ++c) {    // A: 128 rows
            const int rb = c * 32 + wave * 8;
            gload16(A + (long long)(row0 + rb + srow) * lda + k0 + gc * 8,
                    &sA[rb * 64]);
        }
#pragma unroll
        for (int c = 0; c < 2; ++c) {    // B: 64 rows
            const int rb = c * 32 + wave * 8;
            gload16(Bt + (long long)(col0 + rb + srow) * ldb + k0 + gc * 8,
                    &sB[rb * 64]);
        }
        __syncthreads();

#pragma unroll
        for (int kk = 0; kk < 64; kk += 32) {
            const int cb = (lane >> 4) + (kk >> 3);
            const int sl = (cb ^ (lr & 7)) * 8;
            short8 af[2], bf[4];
#pragma unroll
            for (int i = 0; i < 2; ++i)
                af[i] = *(const short8*)(&sA[(wm + i * 16 + lr) * 64 + sl]);
#pragma unroll
            for (int j = 0; j < 4; ++j)
                bf[j] = *(const short8*)(&sB[(j * 16 + lr) * 64 + sl]);
#pragma unroll
            for (int i = 0; i < 2; ++i)
#pragma unroll
                for (int j = 0; j < 4; ++j)
                    acc[i][j] = __builtin_amdgcn_mfma_f32_16x16x32_bf16(
                        af[i], bf[j], acc[i][j], 0, 0, 0);
        }
    }

    const int cr = (lane >> 4) * 4;
    const int cc = lane & 15;
#pragma unroll
    for (int i = 0; i < 2; ++i)
#pragma unroll
        for (int j = 0; j < 4; ++j)
#pragma unroll
            for (int r = 0; r < 4; ++r) {
                int grow = row0 + wm + i * 16 + cr + r;
                int gcol = col0 + j * 16 + cc;
                C[(long long)grow * ldc + gcol] = acc[i][j][r];
            }
}

// ---------- softmax over rows of S (bf16, len 2048) -> P (bf16) ----------
__global__ __launch_bounds__(256) void softmax_rows(
    const u16* __restrict__ S, u16* __restrict__ P, float scale)
{
    const long long row = blockIdx.x;
    const u16* s = S + row * 2048;
    u16* p = P + row * 2048;
    const int t = threadIdx.x;
    const int lane = t & 63, w = t >> 6;

    short8 raw = *(const short8*)(s + t * 8);
    float v[8];
    float m = -1e30f;
#pragma unroll
    for (int i = 0; i < 8; ++i) {
        v[i] = bf16_to_f32((u16)raw[i]) * scale;
        m = fmaxf(m, v[i]);
    }
#pragma unroll
    for (int off = 32; off > 0; off >>= 1) m = fmaxf(m, __shfl_xor(m, off, 64));
    __shared__ float sm[4], ss[4];
    if (lane == 0) sm[w] = m;
    __syncthreads();
    m = fmaxf(fmaxf(sm[0], sm[1]), fmaxf(sm[2], sm[3]));

    float sum = 0.f;
#pragma unroll
    for (int i = 0; i < 8; ++i) {
        v[i] = __expf(v[i] - m);
        sum += v[i];
    }
#pragma unroll
    for (int off = 32; off > 0; off >>= 1) sum += __shfl_xor(sum, off, 64);
    if (lane == 0) ss[w] = sum;
    __syncthreads();
    const float inv = 1.0f / (ss[0] + ss[1] + ss[2] + ss[3]);
    short8 o;
#pragma unroll
    for (int i = 0; i < 8; ++i) o[i] = (short)f32_to_bf16(v[i] * inv);
    *(short8*)(p + t * 8) = o;
}

// ---------- transpose V slice of qkv -> VT[b][d][s] ----------
__global__ void transpose_v(const u16* __restrict__ qkv, u16* __restrict__ VT)
{
    __shared__ u16 tile[32][33];
    const int b  = blockIdx.z;
    const int d0 = blockIdx.x * 32;
    const int s0 = blockIdx.y * 32;
    const int tx = threadIdx.x, ty = threadIdx.y;
#pragma unroll
    for (int i = 0; i < 4; ++i) {
        int s = s0 + ty + i * 8;
        tile[ty + i * 8][tx] =
            qkv[((long long)(b * 2048 + s)) * 3072 + 2048 + d0 + tx];
    }
    __syncthreads();
#pragma unroll
    for (int i = 0; i < 4; ++i) {
        int d = d0 + ty + i * 8;
        VT[((long long)(b * 1024 + d)) * 2048 + s0 + tx] = tile[tx][ty + i * 8];
    }
}

// ---------- launch ----------
extern "C" void kernel_launch(void* const* d_in, const int* in_sizes, int n_in,
                              void* d_out, int out_size, void* d_ws, size_t ws_size,
                              hipStream_t stream) {
    const float* x = (const float*)d_in[0];   // [4,2048,1024]
    const float* W = (const float*)d_in[1];   // [3072,1024]
    float* out = (float*)d_out;               // [4,2048,1024]

    char* ws = (char*)d_ws;
    // layout (bytes): Xb 16M | Wb 6M | QKV 50.3M | VT 16.8M | P 33.6M | S(bf16) 33.6M
    u16*   Xb  = (u16*)(ws);
    u16*   Wb  = (u16*)(ws + 16777216LL);
    u16*   QKV = (u16*)(ws + 23068672LL);
    u16*   VT  = (u16*)(ws + 73400320LL);
    u16*   P   = (u16*)(ws + 90177536LL);
    u16*   S   = (u16*)(ws + 123731968LL);

    // batched S needs 4*2048*2048*2 = 33554432 B on top of 123731968
    const bool batched = (ws_size >= 123731968ULL + 33554432ULL);

    // 1) casts
    cast_f32_bf16_x4<<<8192, 256, 0, stream>>>(x, Xb, 8192 * 1024 / 4);
    cast_f32_bf16_x4<<<3072, 256, 0, stream>>>(W, Wb, 3072 * 1024 / 4);

    // 2) QKV = X * W^T   [8192,3072] bf16
    gemm_bt<u16><<<dim3(24, 64, 1), 256, 0, stream>>>(
        Xb, Wb, QKV, 8192, 3072, 1024, 1024, 1024, 3072, 0, 0, 0);

    // 3) V transpose (all batches)
    transpose_v<<<dim3(32, 64, 4), dim3(32, 8), 0, stream>>>(QKV, VT);

    // 4) S = Q K^T (bf16), softmax -> P (bf16)
    if (batched) {
        gemm_bt<u16><<<dim3(16, 16, 4), 256, 0, stream>>>(
            QKV, QKV + 1024, S, 2048, 2048, 1024, 3072, 3072, 2048,
            2048LL * 3072, 2048LL * 3072, 2048LL * 2048);
        softmax_rows<<<8192, 256, 0, stream>>>(S, P, 0.03125f);
    } else {
        for (int b = 0; b < 4; ++b) {
            const u16* Qb = QKV + (long long)b * 2048 * 3072;
            gemm_bt<u16><<<dim3(16, 16, 1), 256, 0, stream>>>(
                Qb, Qb + 1024, S, 2048, 2048, 1024, 3072, 3072, 2048, 0, 0, 0);
            softmax_rows<<<2048, 256, 0, stream>>>(
                S, P + (long long)b * 2048 * 2048, 0.03125f);
        }
    }

    // 5) Y = P * V  (via VT as Bt), 128x64 tiles -> 1024 blocks (occupancy fix)
    gemm_bt_n64<<<dim3(16, 16, 4), 256, 0, stream>>>(
        P, VT, out, 2048, 1024, 2048, 2048, 2048, 1024,
        2048LL * 2048, 1024LL * 2048, 2048LL * 1024);
}

// Round 6
// 267.397 us; speedup vs baseline: 1.0166x; 1.0166x over previous
//
#include <hip/hip_runtime.h>
#include <hip/hip_bf16.h>

// ---------- types ----------
typedef __attribute__((ext_vector_type(8))) short short8;   // 8 x bf16 (4 VGPRs)
typedef __attribute__((ext_vector_type(4))) float f32x4;    // 16x16 MFMA accumulator

typedef unsigned short u16;

__device__ __forceinline__ u16 f32_to_bf16(float f) {
    unsigned int u = __float_as_uint(f);
    u += 0x7fffu + ((u >> 16) & 1u);   // round-to-nearest-even
    return (u16)(u >> 16);
}
__device__ __forceinline__ float bf16_to_f32(u16 h) {
    return __uint_as_float(((unsigned int)h) << 16);
}

// async global->LDS, 16B per lane; LDS dest = wave-uniform base + lane*16
__device__ __forceinline__ void gload16(const u16* g, u16* lds_base) {
    __builtin_amdgcn_global_load_lds(
        (const __attribute__((address_space(1))) void*)g,
        (__attribute__((address_space(3))) void*)lds_base, 16, 0, 0);
}

// ---------- fused input cast: x then W, fp32 -> bf16, 4 elems/thread ----------
__global__ void cast_inputs(const float* __restrict__ x, u16* __restrict__ Xb,
                            const float* __restrict__ W, u16* __restrict__ Wb,
                            int nx4, int nw4) {
    int i = blockIdx.x * blockDim.x + threadIdx.x;
    const float* in; u16* out; int idx;
    if (i < nx4) { in = x; out = Xb; idx = i; }
    else { idx = i - nx4; if (idx >= nw4) return; in = W; out = Wb; }
    float4 v = ((const float4*)in)[idx];
    ushort4 o;
    o.x = f32_to_bf16(v.x); o.y = f32_to_bf16(v.y);
    o.z = f32_to_bf16(v.z); o.w = f32_to_bf16(v.w);
    ((ushort4*)out)[idx] = o;
}

// ---------- shared GEMM core: 128x128 tile, BK=64, 4 waves 2x2, 4x4 of ----------
// v_mfma_f32_16x16x32_bf16. global_load_lds width=16 staging, XOR chunk swizzle
// (row r slot p holds global chunk p^(r&7)); this exact config measured
// 0 SQ_LDS_BANK_CONFLICT and ~805 TF (R3/R5). 32x32-shape variant measured
// 6.29M conflicts (R4) — don't switch without re-measuring.
struct GemmFrag {
    f32x4 acc[4][4];
    int wm, wn, lane;
};

__device__ __forceinline__ void gemm_core_128(
    const u16* __restrict__ A, const u16* __restrict__ Bt, int K, int lda, int ldb,
    int row0, int col0, u16* sA, u16* sB, GemmFrag& fr)
{
    const int t    = threadIdx.x;
    const int lane = t & 63;
    const int wave = t >> 6;
    fr.lane = lane;
    fr.wm = (wave >> 1) * 64;
    fr.wn = (wave & 1) * 64;
    const int lr = lane & 15;

#pragma unroll
    for (int i = 0; i < 4; ++i)
#pragma unroll
        for (int j = 0; j < 4; ++j)
            fr.acc[i][j] = (f32x4){0.f, 0.f, 0.f, 0.f};

    const int srow = lane >> 3;                    // 0..7 within 8-row group
    const int gc   = (lane & 7) ^ srow;            // swizzled global chunk
    for (int k0 = 0; k0 < K; k0 += 64) {
        __syncthreads();
#pragma unroll
        for (int c = 0; c < 4; ++c) {
            const int rb = c * 32 + wave * 8;      // wave-uniform row base
            const int r  = rb + srow;
            gload16(A  + (long long)(row0 + r) * lda + k0 + gc * 8, &sA[rb * 64]);
            gload16(Bt + (long long)(col0 + r) * ldb + k0 + gc * 8, &sB[rb * 64]);
        }
        __syncthreads();

#pragma unroll
        for (int kk = 0; kk < 64; kk += 32) {
            const int cb = (lane >> 4) + (kk >> 3);   // chunk index 0..7
            const int sl = (cb ^ (lr & 7)) * 8;       // swizzled slot (elems)
            short8 af[4], bf[4];
#pragma unroll
            for (int i = 0; i < 4; ++i) {
                af[i] = *(const short8*)(&sA[(fr.wm + i * 16 + lr) * 64 + sl]);
                bf[i] = *(const short8*)(&sB[(fr.wn + i * 16 + lr) * 64 + sl]);
            }
#pragma unroll
            for (int i = 0; i < 4; ++i)
#pragma unroll
                for (int j = 0; j < 4; ++j)
                    fr.acc[i][j] = __builtin_amdgcn_mfma_f32_16x16x32_bf16(
                        af[i], bf[j], fr.acc[i][j], 0, 0, 0);
        }
    }
}

// ---------- QKV GEMM: Xb[8192,1024] * Wb[3072,1024]^T ----------
// col0 < 2048 -> store bf16 to QKV[row,col] (ld 3072).
// col0 >= 2048 -> V block: store transposed into VT[b][d][s] (packed 8B along s).
__global__ __launch_bounds__(256) void gemm_qkv(
    const u16* __restrict__ Xb, const u16* __restrict__ Wb,
    u16* __restrict__ QKV, u16* __restrict__ VT)
{
    __shared__ u16 sA[128 * 64];
    __shared__ u16 sB[128 * 64];
    const int row0 = blockIdx.y * 128;
    const int col0 = blockIdx.x * 128;
    GemmFrag fr;
    gemm_core_128(Xb, Wb, 1024, 1024, 1024, row0, col0, sA, sB, fr);

    const int cr = (fr.lane >> 4) * 4;    // C/D: col=lane&15, row=(lane>>4)*4+reg
    const int cc = fr.lane & 15;
    if (col0 < 2048) {
#pragma unroll
        for (int i = 0; i < 4; ++i)
#pragma unroll
            for (int j = 0; j < 4; ++j)
#pragma unroll
                for (int r = 0; r < 4; ++r) {
                    int grow = row0 + fr.wm + i * 16 + cr + r;
                    int gcol = col0 + fr.wn + j * 16 + cc;
                    QKV[(long long)grow * 3072 + gcol] = f32_to_bf16(fr.acc[i][j][r]);
                }
    } else {
        // V part: VT[((b*1024)+d)*2048 + s], b = grow>>11, s = grow&2047.
        // 4 consecutive s per (i,j) -> one ushort4 (8B) store.
#pragma unroll
        for (int i = 0; i < 4; ++i) {
            int grow = row0 + fr.wm + i * 16 + cr;   // s base, 4-aligned
            int b = grow >> 11, s = grow & 2047;
#pragma unroll
            for (int j = 0; j < 4; ++j) {
                int d = col0 - 2048 + fr.wn + j * 16 + cc;
                ushort4 o;
                o.x = f32_to_bf16(fr.acc[i][j][0]);
                o.y = f32_to_bf16(fr.acc[i][j][1]);
                o.z = f32_to_bf16(fr.acc[i][j][2]);
                o.w = f32_to_bf16(fr.acc[i][j][3]);
                *(ushort4*)(&VT[((long long)(b * 1024 + d)) * 2048 + s]) = o;
            }
        }
    }
}

// ---------- S GEMM: S[b] = Q[b] * K[b]^T  (bf16 out, z-batched) ----------
__global__ __launch_bounds__(256) void gemm_s(
    const u16* __restrict__ QKV, u16* __restrict__ S)
{
    __shared__ u16 sA[128 * 64];
    __shared__ u16 sB[128 * 64];
    const long long boff = (long long)blockIdx.z * 2048 * 3072;
    const u16* Q = QKV + boff;
    const u16* K = QKV + boff + 1024;
    u16* Sb = S + (long long)blockIdx.z * 2048 * 2048;
    const int row0 = blockIdx.y * 128;
    const int col0 = blockIdx.x * 128;
    GemmFrag fr;
    gemm_core_128(Q, K, 1024, 3072, 3072, row0, col0, sA, sB, fr);

    const int cr = (fr.lane >> 4) * 4;
    const int cc = fr.lane & 15;
#pragma unroll
    for (int i = 0; i < 4; ++i)
#pragma unroll
        for (int j = 0; j < 4; ++j)
#pragma unroll
            for (int r = 0; r < 4; ++r) {
                int grow = row0 + fr.wm + i * 16 + cr + r;
                int gcol = col0 + fr.wn + j * 16 + cc;
                Sb[(long long)grow * 2048 + gcol] = f32_to_bf16(fr.acc[i][j][r]);
            }
}

// ---------- PV GEMM: Y[b] = P[b] * VT[b]^T  (fp32 out, z-batched) ----------
__global__ __launch_bounds__(256) void gemm_pv(
    const u16* __restrict__ P, const u16* __restrict__ VT,
    float* __restrict__ Y)
{
    __shared__ u16 sA[128 * 64];
    __shared__ u16 sB[128 * 64];
    const u16* Pb  = P  + (long long)blockIdx.z * 2048 * 2048;
    const u16* VTb = VT + (long long)blockIdx.z * 1024 * 2048;
    float* Yb = Y + (long long)blockIdx.z * 2048 * 1024;
    const int row0 = blockIdx.y * 128;
    const int col0 = blockIdx.x * 128;
    GemmFrag fr;
    gemm_core_128(Pb, VTb, 2048, 2048, 2048, row0, col0, sA, sB, fr);

    const int cr = (fr.lane >> 4) * 4;
    const int cc = fr.lane & 15;
#pragma unroll
    for (int i = 0; i < 4; ++i)
#pragma unroll
        for (int j = 0; j < 4; ++j)
#pragma unroll
            for (int r = 0; r < 4; ++r) {
                int grow = row0 + fr.wm + i * 16 + cr + r;
                int gcol = col0 + fr.wn + j * 16 + cc;
                Yb[(long long)grow * 1024 + gcol] = fr.acc[i][j][r];
            }
}

// ---------- softmax over rows of S (bf16, len 2048) -> P (bf16) ----------
__global__ __launch_bounds__(256) void softmax_rows(
    const u16* __restrict__ S, u16* __restrict__ P, float scale)
{
    const long long row = blockIdx.x;
    const u16* s = S + row * 2048;
    u16* p = P + row * 2048;
    const int t = threadIdx.x;
    const int lane = t & 63, w = t >> 6;

    short8 raw = *(const short8*)(s + t * 8);
    float v[8];
    float m = -1e30f;
#pragma unroll
    for (int i = 0; i < 8; ++i) {
        v[i] = bf16_to_f32((u16)raw[i]) * scale;
        m = fmaxf(m, v[i]);
    }
#pragma unroll
    for (int off = 32; off > 0; off >>= 1) m = fmaxf(m, __shfl_xor(m, off, 64));
    __shared__ float sm[4], ss[4];
    if (lane == 0) sm[w] = m;
    __syncthreads();
    m = fmaxf(fmaxf(sm[0], sm[1]), fmaxf(sm[2], sm[3]));

    float sum = 0.f;
#pragma unroll
    for (int i = 0; i < 8; ++i) {
        v[i] = __expf(v[i] - m);
        sum += v[i];
    }
#pragma unroll
    for (int off = 32; off > 0; off >>= 1) sum += __shfl_xor(sum, off, 64);
    if (lane == 0) ss[w] = sum;
    __syncthreads();
    const float inv = 1.0f / (ss[0] + ss[1] + ss[2] + ss[3]);
    short8 o;
#pragma unroll
    for (int i = 0; i < 8; ++i) o[i] = (short)f32_to_bf16(v[i] * inv);
    *(short8*)(p + t * 8) = o;
}

// ---------- launch ----------
extern "C" void kernel_launch(void* const* d_in, const int* in_sizes, int n_in,
                              void* d_out, int out_size, void* d_ws, size_t ws_size,
                              hipStream_t stream) {
    const float* x = (const float*)d_in[0];   // [4,2048,1024]
    const float* W = (const float*)d_in[1];   // [3072,1024]
    float* out = (float*)d_out;               // [4,2048,1024]

    char* ws = (char*)d_ws;
    // layout (bytes): Xb 16M | Wb 6M | QKV 50.3M | VT 16.8M | P 33.6M | S(bf16) 33.6M
    u16*   Xb  = (u16*)(ws);
    u16*   Wb  = (u16*)(ws + 16777216LL);
    u16*   QKV = (u16*)(ws + 23068672LL);
    u16*   VT  = (u16*)(ws + 73400320LL);
    u16*   P   = (u16*)(ws + 90177536LL);
    u16*   S   = (u16*)(ws + 123731968LL);

    // batched S needs 4*2048*2048*2 = 33554432 B on top of 123731968
    const bool batched = (ws_size >= 123731968ULL + 33554432ULL);

    // 1) fused casts (x then W)
    cast_inputs<<<11264, 256, 0, stream>>>(x, Xb, W, Wb,
                                           8192 * 1024 / 4, 3072 * 1024 / 4);

    // 2) QKV = X * W^T; V columns written transposed into VT
    gemm_qkv<<<dim3(24, 64, 1), 256, 0, stream>>>(Xb, Wb, QKV, VT);

    // 3) S = Q K^T (bf16), softmax -> P (bf16)
    if (batched) {
        gemm_s<<<dim3(16, 16, 4), 256, 0, stream>>>(QKV, S);
        softmax_rows<<<8192, 256, 0, stream>>>(S, P, 0.03125f);
    } else {
        for (int b = 0; b < 4; ++b) {
            gemm_s<<<dim3(16, 16, 1), 256, 0, stream>>>(
                QKV + (long long)b * 2048 * 3072 - (long long)b * 2048 * 3072 + (long long)b * 2048 * 3072,
                S);
            // note: fallback uses z=0 base; shift pointers manually
            softmax_rows<<<2048, 256, 0, stream>>>(
                S, P + (long long)b * 2048 * 2048, 0.03125f);
        }
    }

    // 4) Y = P * VT^T (fp32 out)
    gemm_pv<<<dim3(8, 16, 4), 256, 0, stream>>>(P, VT, out);
}